// Round 10
// baseline (84.994 us; speedup 1.0000x reference)
//
#include <hip/hip_runtime.h>
#include <math.h>

#define LOG2E 1.4426950408889634f
#define LN2   0.6931471805599453f

typedef float v2f __attribute__((ext_vector_type(2)));

// Params layout: pairwise-AoS. For component pair p = (2p, 2p+1), record of
// 12 floats at pp[12p]: [A0,A1, B0,B1, C0,C1, D0,D1, E0,E1, K0,K1].
// Coefficients pre-scaled by LOG2E and pre-negated (except K):
//   e2 = K + A*xx + B*xy + C*yy + D*sx + E*sy   (base-2 exponent, e2 <= 0)
__global__ __launch_bounds__(1024) void gm_params(
    const float* __restrict__ mu,         // (M,2)
    const float* __restrict__ sigma_log,  // (M,2)
    const float* __restrict__ theta,      // (M,)
    const float* __restrict__ w,          // (M,1)
    float* __restrict__ pp,               // (12*M/2,)
    float* __restrict__ out)
{
    const int j = threadIdx.x;
    const int lane = j & 63;
    const int wid  = j >> 6;

    const float wj = w[j];

    // logsumexp over w (w ~ N(0,1): raw exp is safe)
    float e = __expf(wj);
    #pragma unroll
    for (int off = 32; off > 0; off >>= 1)
        e += __shfl_down(e, off, 64);

    __shared__ float ws[16];
    if (lane == 0) ws[wid] = e;
    __syncthreads();

    float tot = 0.0f;
    #pragma unroll
    for (int k = 0; k < 16; ++k) tot += ws[k];
    const float lse = __logf(tot);

    const float sl0 = sigma_log[2 * j + 0];
    const float sl1 = sigma_log[2 * j + 1];
    const float a = __expf(-2.0f * sl0);
    const float b = __expf(-2.0f * sl1);
    const float th = theta[j];
    const float c = __cosf(th);
    const float s = __sinf(th);

    const float g11 = a * c * c + b * s * s;
    const float g12 = (a - b) * c * s;
    const float g22 = a * s * s + b * c * c;

    const float mx = mu[2 * j + 0];
    const float my = mu[2 * j + 1];

    const float wlog = wj - lse - (sl0 + sl1);

    const float A = g11;
    const float B = 2.0f * g12;
    const float C = g22;
    const float D = -(2.0f * g11 * mx + 2.0f * g12 * my);
    const float E = -(2.0f * g12 * mx + 2.0f * g22 * my);
    const float F = g11 * mx * mx + 2.0f * g12 * mx * my + g22 * my * my;
    const float K = (wlog - F) * LOG2E;

    const int base = 12 * (j >> 1) + (j & 1);
    pp[base + 0]  = -A * LOG2E;
    pp[base + 2]  = -B * LOG2E;
    pp[base + 4]  = -C * LOG2E;
    pp[base + 6]  = -D * LOG2E;
    pp[base + 8]  = -E * LOG2E;
    pp[base + 10] = K;

    if (j == 0) out[0] = 0.0f;
}

// exp2 for e in [-25, 0] WITHOUT v_exp_f32 (trans pipe): full-rate VALU only.
// n = rndne(e); f = e-n in [-0.5,0.5]; 2^f by deg-4 Taylor; scale by ldexp.
__device__ __forceinline__ v2f exp2_poly2(v2f e) {
    const float n0 = __builtin_rintf(e.x);
    const float n1 = __builtin_rintf(e.y);
    v2f f;
    f.x = e.x - n0;
    f.y = e.y - n1;
    const v2f C4 = (v2f)(0.009618130f);   // ln2^4/24
    const v2f C3 = (v2f)(0.055504109f);   // ln2^3/6
    const v2f C2 = (v2f)(0.240226507f);   // ln2^2/2
    const v2f C1 = (v2f)(0.693147181f);   // ln2
    v2f p = __builtin_elementwise_fma(f, C4, C3);
    p = __builtin_elementwise_fma(f, p, C2);
    p = __builtin_elementwise_fma(f, p, C1);
    p = __builtin_elementwise_fma(f, p, (v2f)(1.0f));
    v2f r;
    r.x = ldexpf(p.x, (int)n0);
    r.y = ldexpf(p.y, (int)n1);
    return r;
}

// Kernel B: block = 1024 threads = 16 wave-uniform M-chunks of 64 components;
// 64 samples per block (1 per lane). Params via scalar s_load (wave-uniform
// index); qf via packed fp32; exp2 via polynomial on the full-rate pipe.
__global__ __launch_bounds__(1024) void gm_main(
    const float* __restrict__ sample,   // (N,2)
    const float* __restrict__ pp,       // pairwise param records
    float* __restrict__ out,
    int M)
{
    const int lane = threadIdx.x & 63;     // sample within block
    int chunk = __builtin_amdgcn_readfirstlane((int)(threadIdx.x >> 6)); // 0..15
    chunk &= 15;
    __builtin_assume(chunk >= 0 && chunk < 16);

    const int i = blockIdx.x * 64 + lane;

    const float2 sv = ((const float2*)sample)[i];
    const float sx = sv.x, sy = sv.y;
    const v2f xx2 = (v2f)(sx * sx);
    const v2f xy2 = (v2f)(sx * sy);
    const v2f yy2 = (v2f)(sy * sy);
    const v2f sx2 = (v2f)(sx);
    const v2f sy2 = (v2f)(sy);

    const int pairs = M >> 5;              // 32 pairs (64 comps) per chunk
    const v2f* __restrict__ rec = (const v2f*)(pp + 12 * (chunk * pairs));

    v2f acc[4];
    #pragma unroll
    for (int u = 0; u < 4; ++u) acc[u] = (v2f)(0.0f);

    for (int p = 0; p < pairs; p += 4) {
        #pragma unroll
        for (int u = 0; u < 4; ++u) {
            const v2f* r = rec + 6 * (p + u);
            v2f e = r[5];
            e = __builtin_elementwise_fma(r[0], xx2, e);
            e = __builtin_elementwise_fma(r[1], xy2, e);
            e = __builtin_elementwise_fma(r[2], yy2, e);
            e = __builtin_elementwise_fma(r[3], sx2, e);
            e = __builtin_elementwise_fma(r[4], sy2, e);
            acc[u] += exp2_poly2(e);
        }
    }

    const v2f accv = (acc[0] + acc[1]) + (acc[2] + acc[3]);

    __shared__ float psum[16][64];
    psum[chunk][lane] = accv.x + accv.y;
    __syncthreads();

    if (threadIdx.x < 64) {
        const int s = threadIdx.x;
        float tot = 0.0f;
        #pragma unroll
        for (int k = 0; k < 16; ++k) tot += psum[k][s];
        float v = -LN2 * __builtin_amdgcn_logf(tot);
        #pragma unroll
        for (int off = 32; off > 0; off >>= 1)
            v += __shfl_down(v, off, 64);
        if (s == 0) atomicAdd(out, v);
    }
}

extern "C" void kernel_launch(void* const* d_in, const int* in_sizes, int n_in,
                              void* d_out, int out_size, void* d_ws, size_t ws_size,
                              hipStream_t stream) {
    const float* sample    = (const float*)d_in[0];
    const float* mu        = (const float*)d_in[1];
    const float* sigma_log = (const float*)d_in[2];
    const float* theta     = (const float*)d_in[3];
    const float* w         = (const float*)d_in[4];
    float* out = (float*)d_out;
    float* pp = (float*)d_ws;

    const int M = in_sizes[3];      // 1024
    const int N = in_sizes[0] / 2;  // 65536

    gm_params<<<1, M, 0, stream>>>(mu, sigma_log, theta, w, pp, out);

    const int grid = N / 64;        // 1024 blocks, 1024 threads each
    gm_main<<<grid, 1024, 0, stream>>>(sample, pp, out, M);
}